// Round 6
// baseline (382.171 us; speedup 1.0000x reference)
//
#include <hip/hip_runtime.h>
#include <hip/hip_bf16.h>

typedef unsigned short u16;
typedef unsigned int   u32;
typedef __bf16 bf16x8 __attribute__((ext_vector_type(8)));
typedef float  f32x4  __attribute__((ext_vector_type(4)));
typedef float  f32x16 __attribute__((ext_vector_type(16)));
typedef u16    u16x8  __attribute__((ext_vector_type(8)));
typedef u32    u32x2  __attribute__((ext_vector_type(2)));

#define GAS __attribute__((address_space(1)))
#define LAS __attribute__((address_space(3)))

__device__ __forceinline__ void gload_lds16(const void* g, void* lds) {
  __builtin_amdgcn_global_load_lds((GAS u32*)g, (LAS u32*)lds, 16, 0, 0);
}

__device__ __forceinline__ u16 f2bf(float f) {
  union { float f; u32 u; } v; v.f = f;
  u32 r = v.u + 0x7FFFu + ((v.u >> 16) & 1u);   // round-to-nearest-even
  return (u16)(r >> 16);
}

__device__ __forceinline__ u32 cvtpk_bf16(float lo, float hi) {
  u32 r;
  asm("v_cvt_pk_bf16_f32 %0, %1, %2" : "=v"(r) : "v"(lo), "v"(hi));
  return r;
}

// ---------------- elementwise cast x: f32 -> bf16 (8 elems/thread) ----------------
__global__ __launch_bounds__(256) void cast_x_kernel(const float* __restrict__ x,
                                                     u16* __restrict__ xb) {
  int i = (blockIdx.x * 256 + threadIdx.x) * 8;
  float4 a = *(const float4*)(x + i);
  float4 b = *(const float4*)(x + i + 4);
  u16x8 o;
  o[0] = f2bf(a.x); o[1] = f2bf(a.y); o[2] = f2bf(a.z); o[3] = f2bf(a.w);
  o[4] = f2bf(b.x); o[5] = f2bf(b.y); o[6] = f2bf(b.z); o[7] = f2bf(b.w);
  *(u16x8*)(xb + i) = o;
}

// ---------------- transpose-cast: W[k][n] f32 -> WT[n][k] bf16 (times scale) ------
__global__ __launch_bounds__(256) void transcast(const float* __restrict__ W,
                                                 u16* __restrict__ WT, int dim,
                                                 float scale) {
  __shared__ float t[32][33];
  int tx = threadIdx.x, ty = threadIdx.y;      // 32 x 8
  int c0 = blockIdx.x * 32, r0 = blockIdx.y * 32;
#pragma unroll
  for (int i = 0; i < 4; ++i)
    t[ty + i * 8][tx] = W[(r0 + ty + i * 8) * dim + c0 + tx];
  __syncthreads();
#pragma unroll
  for (int i = 0; i < 4; ++i)
    WT[(c0 + ty + i * 8) * dim + r0 + tx] = f2bf(t[tx][ty + i * 8] * scale);
}

// ---------------- GEMM: C[M][N] = A[M][K] * B^T (B stored [N][K]) ----------------
template <int OUTF32>
__global__ __launch_bounds__(256) void gemm_bt(
    const u16* __restrict__ A, const u16* __restrict__ B,
    float* __restrict__ Cf, u16* __restrict__ Cb, const float* __restrict__ bias,
    int M, int N, int K, int lda, int ldb, int ldc) {
  __shared__ alignas(16) u16 As[128 * 32];
  __shared__ alignas(16) u16 Bs[128 * 32];
  const int tid = threadIdx.x;
  const int lane = tid & 63, wave = tid >> 6;
  const int wm = wave >> 1, wn = wave & 1;
  const int r15 = lane & 15, g = lane >> 4;
  const int tm = blockIdx.x * 128, tn = blockIdx.y * 128;

  int aoff[2], boff[2], sbase[2];
#pragma unroll
  for (int i = 0; i < 2; ++i) {
    int c = (i * 4 + wave) * 64 + lane;       // 0..511
    int row = c >> 2;
    int q = (c & 3) ^ ((row >> 1) & 3);
    aoff[i] = (tm + row) * lda + q * 8;
    boff[i] = (tn + row) * ldb + q * 8;
    sbase[i] = (i * 4 + wave) * 1024;
  }
  const int sw = (r15 >> 1) & 3;
  int ard[4], brd[4];
#pragma unroll
  for (int t = 0; t < 4; ++t) {
    ard[t] = (wm * 64 + t * 16 + r15) * 64 + ((g ^ sw) << 4);
    brd[t] = (wn * 64 + t * 16 + r15) * 64 + ((g ^ sw) << 4);
  }

  f32x4 acc[4][4] = {};

  for (int k0 = 0; k0 < K; k0 += 32) {
    __syncthreads();
#pragma unroll
    for (int i = 0; i < 2; ++i) {
      gload_lds16(A + aoff[i] + k0, (char*)As + sbase[i]);
      gload_lds16(B + boff[i] + k0, (char*)Bs + sbase[i]);
    }
    __syncthreads();
    bf16x8 af[4], bfr[4];
#pragma unroll
    for (int t = 0; t < 4; ++t) {
      af[t]  = *(const bf16x8*)((const char*)As + ard[t]);
      bfr[t] = *(const bf16x8*)((const char*)Bs + brd[t]);
    }
#pragma unroll
    for (int mi = 0; mi < 4; ++mi)
#pragma unroll
      for (int ni = 0; ni < 4; ++ni)
        acc[mi][ni] = __builtin_amdgcn_mfma_f32_16x16x32_bf16(af[mi], bfr[ni],
                                                              acc[mi][ni], 0, 0, 0);
  }

#pragma unroll
  for (int mi = 0; mi < 4; ++mi)
#pragma unroll
    for (int ni = 0; ni < 4; ++ni)
#pragma unroll
      for (int r = 0; r < 4; ++r) {
        int m = tm + wm * 64 + mi * 16 + g * 4 + r;
        int n = tn + wn * 64 + ni * 16 + r15;
        float v = acc[mi][ni][r];
        if (OUTF32) Cf[m * ldc + n] = v + bias[n];
        else        Cb[m * ldc + n] = f2bf(v);
      }
}

// ---------------- flash attention: 32x32 MFMA, zero-shuffle P->PV -----------------
// QK:  [B*S][4096] bf16 rows = {Q[h][d], K_scaled[h][d]}  (K pre-scaled by C2)
// VtG: [2048][4096] bf16 = V^T, row (h*128+d), col (b*2048+s)
// O:   [B*S][2048] bf16
// Block: 4 waves x 32 q-rows = 128 q. KVBLK=64, dbuf K and V, counted vmcnt(8).
// Key trick: kv->k-slot placement f(u,hi,j) = 16u + 4hi + (j&3) + 8*(j>>2) for the
// PV MFMA matches the 32x32 C-layout's per-lane kv ownership exactly, so the
// B-fragment is pk[kvh][4u..4u+3] with NO cross-lane movement; V^T's A-fragment
// uses the same placement via two 8B LDS reads.
__global__ __launch_bounds__(256) void attn_kernel(const u16* __restrict__ QK,
                                                   const u16* __restrict__ VtG,
                                                   u16* __restrict__ O) {
  __shared__ alignas(16) u16 Ks[2][64 * 128];   // 16KB each
  __shared__ alignas(16) u16 Vs[2][128 * 64];   // 16KB each

  const int tid = threadIdx.x, lane = tid & 63, wave = tid >> 6;
  const int c31 = lane & 31, hi = lane >> 5;
  const int qb = blockIdx.x, h = blockIdx.y, b = blockIdx.z;

  const u16* Qp = QK + (size_t)b * 2048 * 4096 + h * 128;
  const u16* Kp = Qp + 2048;
  const u16* Vp = VtG + (size_t)(h * 128) * 4096 + b * 2048;

  // Q fragments: lane owns q-col c31; d = c*16 + hi*8 + j
  const int qrow = qb * 128 + wave * 32 + c31;
  bf16x8 qf[8];
#pragma unroll
  for (int c = 0; c < 8; ++c)
    qf[c] = *(const bf16x8*)(Qp + (size_t)qrow * 4096 + c * 16 + hi * 8);
  asm volatile("s_waitcnt vmcnt(0)" ::: "memory");

  // staging: 1024 16B-chunks per tile; wave-uniform LDS base (R4-proven pattern)
  int koff[4], voff[4];
#pragma unroll
  for (int i = 0; i < 4; ++i) {
    int c = (i * 4 + wave) * 64 + lane;        // 0..1023, contiguous per wave
    int kr = c >> 4, kj = c & 15;              // K rows of 128 elems (16 chunks)
    koff[i] = kr * 4096 + (kj ^ (kr & 7)) * 8;
    int vr = c >> 3, vj = c & 7;               // V^T rows of 64 elems (8 chunks)
    voff[i] = vr * 4096 + (vj ^ (vr & 7)) * 8;
  }
  const int sw = lane & 7;                     // == row&7 for all fragment rows

  f32x16 oaccT[4] = {};                        // O^T: d = dt*32+(r&3)+8(r>>2)+4hi, q = c31
  float m = -1e30f, l = 0.f;

  // prologue: stage tile 0
#pragma unroll
  for (int i = 0; i < 4; ++i) {
    gload_lds16(Kp + koff[i], (char*)Ks[0] + (i * 4 + wave) * 1024);
    gload_lds16(Vp + voff[i], (char*)Vs[0] + (i * 4 + wave) * 1024);
  }

  for (int t = 0; t < 32; ++t) {
    const int cur = t & 1;
    if (t < 31) {
      const size_t kv0n = (size_t)(t + 1) * 64;
#pragma unroll
      for (int i = 0; i < 4; ++i) {
        gload_lds16(Kp + kv0n * 4096 + koff[i], (char*)Ks[cur ^ 1] + (i * 4 + wave) * 1024);
        gload_lds16(Vp + kv0n + voff[i], (char*)Vs[cur ^ 1] + (i * 4 + wave) * 1024);
      }
      asm volatile("s_waitcnt vmcnt(8)" ::: "memory");  // drain tile t, keep t+1 in flight
    } else {
      asm volatile("s_waitcnt vmcnt(0)" ::: "memory");
    }
    __builtin_amdgcn_s_barrier();
    __builtin_amdgcn_sched_barrier(0);

    // S^T = K_scaled · Q^T : sacc[kvh] covers kv = kvh*32 + (r&3)+8(r>>2)+4hi, q = c31
    f32x16 sacc[2] = {};
    __builtin_amdgcn_s_setprio(1);
#pragma unroll
    for (int kvh = 0; kvh < 2; ++kvh) {
      const int r = kvh * 32 + c31;
#pragma unroll
      for (int c = 0; c < 8; ++c) {
        bf16x8 kf = *(const bf16x8*)((const char*)Ks[cur] + r * 256 +
                                     (((2 * c + hi) ^ sw) << 4));
        sacc[kvh] = __builtin_amdgcn_mfma_f32_32x32x16_bf16(kf, qf[c], sacc[kvh], 0, 0, 0);
      }
    }
    __builtin_amdgcn_s_setprio(0);

    // lane-local online softmax (log2 domain); partner lane = lane^32
    float mx = sacc[0][0];
#pragma unroll
    for (int kvh = 0; kvh < 2; ++kvh)
#pragma unroll
      for (int r = 0; r < 16; ++r) mx = fmaxf(mx, sacc[kvh][r]);
    mx = fmaxf(mx, __shfl_xor(mx, 32));

    if (!__all(mx - m <= 8.0f)) {              // defer-max
      float mn = fmaxf(m, mx);
      float alpha = __builtin_amdgcn_exp2f(m - mn);
#pragma unroll
      for (int dt = 0; dt < 4; ++dt) oaccT[dt] *= alpha;
      l *= alpha;
      m = mn;
    }

    float rs = 0.f;
    u32 pk[2][8];    // pk[kvh][w] = bf16pair for kv = 32kvh + 8(w>>1) + 4hi + 2(w&1) + {0,1}
#pragma unroll
    for (int kvh = 0; kvh < 2; ++kvh)
#pragma unroll
      for (int w = 0; w < 8; ++w) {
        float p0 = __builtin_amdgcn_exp2f(sacc[kvh][2 * w] - m);
        float p1 = __builtin_amdgcn_exp2f(sacc[kvh][2 * w + 1] - m);
        rs += p0 + p1;
        pk[kvh][w] = cvtpk_bf16(p0, p1);
      }
    rs += __shfl_xor(rs, 32);
    l += rs;

    // O^T += V^T · P^T  — B = pk words directly (placement matches C-layout ownership);
    // A = V^T with the same placement: k-slot (hi,j) <- kv = 16u+4hi+(j&3)+8*(j>>2)
    __builtin_amdgcn_s_setprio(1);
#pragma unroll
    for (int dt = 0; dt < 4; ++dt) {
      const int r = dt * 32 + c31;
      const char* vrow = (const char*)Vs[cur] + r * 128 + 8 * hi;
#pragma unroll
      for (int kvh = 0; kvh < 2; ++kvh)
#pragma unroll
        for (int u = 0; u < 2; ++u) {
          const int c0 = 4 * kvh + 2 * u;
          union { u32 u4[4]; bf16x8 v; } af, bfv;
          *(u32x2*)&af.u4[0] = *(const u32x2*)(vrow + ((c0 ^ sw) << 4));
          *(u32x2*)&af.u4[2] = *(const u32x2*)(vrow + (((c0 + 1) ^ sw) << 4));
          bfv.u4[0] = pk[kvh][4 * u + 0];
          bfv.u4[1] = pk[kvh][4 * u + 1];
          bfv.u4[2] = pk[kvh][4 * u + 2];
          bfv.u4[3] = pk[kvh][4 * u + 3];
          oaccT[dt] = __builtin_amdgcn_mfma_f32_32x32x16_bf16(af.v, bfv.v, oaccT[dt], 0, 0, 0);
        }
    }
    __builtin_amdgcn_s_setprio(0);

    __builtin_amdgcn_s_barrier();              // all waves done with buf[cur]
  }

  // epilogue: per-lane q = qrow; d = dt*32 + 8s + 4hi + {0..3} from regs 4s..4s+3
  const float inv = 1.0f / l;
  u16* Ob = O + ((size_t)(b * 2048 + qrow)) * 2048 + h * 128;
#pragma unroll
  for (int dt = 0; dt < 4; ++dt)
#pragma unroll
    for (int s = 0; s < 4; ++s) {
      u32x2 pair;
      pair[0] = cvtpk_bf16(oaccT[dt][4 * s + 0] * inv, oaccT[dt][4 * s + 1] * inv);
      pair[1] = cvtpk_bf16(oaccT[dt][4 * s + 2] * inv, oaccT[dt][4 * s + 3] * inv);
      *(u32x2*)(Ob + dt * 32 + 8 * s + 4 * hi) = pair;
    }
}

// ---------------- host ----------------
extern "C" void kernel_launch(void* const* d_in, const int* in_sizes, int n_in,
                              void* d_out, int out_size, void* d_ws, size_t ws_size,
                              hipStream_t stream) {
  const float* x  = (const float*)d_in[0];
  const float* Wq = (const float*)d_in[1];
  const float* Wk = (const float*)d_in[2];
  const float* Wv = (const float*)d_in[3];
  const float* Wo = (const float*)d_in[4];
  const float* bo = (const float*)d_in[5];
  float* out = (float*)d_out;

  char* ws = (char*)d_ws;
  u16* xb    = (u16*)ws;                               // 16 MiB (reused as attn O)
  u16* WqkvT = (u16*)(ws + (size_t)16 * 1024 * 1024);  // 24 MiB [6144][2048]
  u16* WoT   = (u16*)(ws + (size_t)40 * 1024 * 1024);  // 8 MiB  [2048][2048]
  u16* QK    = (u16*)(ws + (size_t)48 * 1024 * 1024);  // 32 MiB [4096][4096]
  u16* VtG   = (u16*)(ws + (size_t)80 * 1024 * 1024);  // 16 MiB [2048][4096]
  u16* Oattn = xb;

  const float C2 = 0.12753102f;   // (1/sqrt(128)) * log2(e), folded into Wk

  cast_x_kernel<<<4096, 256, 0, stream>>>(x, xb);
  dim3 tb(32, 8), tg(64, 64);
  transcast<<<tg, tb, 0, stream>>>(Wq, WqkvT, 2048, 1.0f);
  transcast<<<tg, tb, 0, stream>>>(Wk, WqkvT + 2048 * 2048, 2048, C2);
  transcast<<<tg, tb, 0, stream>>>(Wv, WqkvT + 2 * 2048 * 2048, 2048, 1.0f);
  transcast<<<tg, tb, 0, stream>>>(Wo, WoT, 2048, 1.0f);

  // QK = xb @ [Wq|Wk_scaled]   (M=4096, N=4096, K=2048)
  gemm_bt<0><<<dim3(32, 32), 256, 0, stream>>>(xb, WqkvT, nullptr, QK, nullptr,
                                               4096, 4096, 2048, 2048, 2048, 4096);
  // V^T = Wv^T @ x^T    (M=2048, N=4096, K=2048) -> [h*128+d][b*2048+s]
  gemm_bt<0><<<dim3(16, 32), 256, 0, stream>>>(WqkvT + (size_t)4096 * 2048, xb,
                                               nullptr, VtG, nullptr,
                                               2048, 4096, 2048, 2048, 2048, 4096);
  // attention: 128 q-rows per block
  attn_kernel<<<dim3(16, 16, 2), 256, 0, stream>>>(QK, VtG, Oattn);
  // out = O @ Wo + bo   (M=4096, N=2048, K=2048), f32 out
  gemm_bt<1><<<dim3(32, 16), 256, 0, stream>>>(Oattn, WoT, out, nullptr, bo,
                                               4096, 2048, 2048, 2048, 2048, 2048);
}